// Round 4
// baseline (224.707 us; speedup 1.0000x reference)
//
#include <hip/hip_runtime.h>

typedef unsigned short u16;
typedef short short8v __attribute__((ext_vector_type(8)));
typedef float float4v __attribute__((ext_vector_type(4)));
typedef unsigned short ushort4v __attribute__((ext_vector_type(4)));

// ---------------- LDS layout (u16 element offsets) ----------------
// Region A: C1qk [64 tok][392]  (Q ch 0..191, K ch 192..383, pad)  = 25088 u16
//   overlays: Xs [64][216] (phase 0/1a), P[wave][64][72] (phase 2b, 4*4608),
//             Ostage [64][216] (phase 2c/3)
// Region B: VS [8 hp][24 d][72 m] (V transposed)                   = 13824 u16
#define XLD   216
#define C1LD  392
#define VSLD  72
#define PLD   72
#define VS_OFF (64*C1LD)
#define LDS_U16 (VS_OFF + 8*24*VSLD)   // 38912 u16
#define LDS_BYTES (LDS_U16*2)          // 77824 B -> 2 blocks/CU

// lgkm-only barrier: LDS visibility without draining in-flight global loads
#define SOFT_BAR() do { asm volatile("s_waitcnt lgkmcnt(0)" ::: "memory"); \
                        __builtin_amdgcn_s_barrier(); } while(0)

__device__ __forceinline__ u16 f2bf(float f){
  unsigned u = __builtin_bit_cast(unsigned, f);
  return (u16)((u + 0x7FFFu + ((u >> 16) & 1u)) >> 16);
}

// ---------------- prep: convert weights to bf16 ----------------
__global__ void prep_convert(const float* __restrict__ qkv_w, const float* __restrict__ proj_w,
                             u16* __restrict__ Wq, u16* __restrict__ Wp){
  int idx = blockIdx.x*blockDim.x + threadIdx.x;
  const int total = 110592 + 36864;
  for (; idx < total; idx += gridDim.x*blockDim.x){
    if (idx < 110592) Wq[idx] = f2bf(qkv_w[idx]);
    else              Wp[idx-110592] = f2bf(proj_w[idx-110592]);
  }
}

__device__ __forceinline__ void lnrelu6(float* v, const float* g, const float* b){
  float mu = (v[0]+v[1]+v[2]+v[3]+v[4]+v[5]) * (1.0f/6.0f);
  float var = 0.f;
  #pragma unroll
  for (int j=0;j<6;++j){ float d = v[j]-mu; var += d*d; }
  var *= (1.0f/6.0f);
  float inv = rsqrtf(var + 1e-5f);
  #pragma unroll
  for (int j=0;j<6;++j) v[j] = fmaxf((v[j]-mu)*inv*g[j] + b[j], 0.f);
}

// ---------------- prep: rel-pos bias table, biasT[(i*4+h)][n=query][m=key] ----------------
__global__ void prep_bias(const float* __restrict__ ppw, const float* __restrict__ ppb,
                          const float* __restrict__ ln1g, const float* __restrict__ ln1b,
                          const float* __restrict__ fc1w, const float* __restrict__ fc1b,
                          const float* __restrict__ ln2g, const float* __restrict__ ln2b,
                          const float* __restrict__ fc2w, const float* __restrict__ fc2b,
                          const float* __restrict__ ln3g, const float* __restrict__ ln3b,
                          const float* __restrict__ fc3w, const float* __restrict__ fc3b,
                          float* __restrict__ biasT){
  __shared__ float pos3[2][225][4];
  const int t = threadIdx.x;
  if (t < 225){
    const float dy = (float)(t/15) - 7.0f;
    const float dx = (float)(t%15) - 7.0f;
    for (int i=0;i<2;++i){
      float v[6], y[6];
      #pragma unroll
      for (int j=0;j<6;++j)
        v[j] = dy*ppw[(i*6+j)*2+0] + dx*ppw[(i*6+j)*2+1] + ppb[i*6+j];
      lnrelu6(v, ln1g+i*6, ln1b+i*6);
      #pragma unroll
      for (int j=0;j<6;++j){
        float a = fc1b[i*6+j];
        #pragma unroll
        for (int k=0;k<6;++k) a += v[k]*fc1w[(i*6+j)*6+k];
        y[j] = a;
      }
      lnrelu6(y, ln2g+i*6, ln2b+i*6);
      #pragma unroll
      for (int j=0;j<6;++j){
        float a = fc2b[i*6+j];
        #pragma unroll
        for (int k=0;k<6;++k) a += y[k]*fc2w[(i*6+j)*6+k];
        v[j] = a;
      }
      lnrelu6(v, ln3g+i*6, ln3b+i*6);
      #pragma unroll
      for (int h=0;h<4;++h){
        float a = fc3b[i*4+h];
        #pragma unroll
        for (int k=0;k<6;++k) a += v[k]*fc3w[(i*4+h)*6+k];
        pos3[i][t][h] = a;
      }
    }
  }
  __syncthreads();
  // biasT[(i*4+h)*4096 + n*64 + m] = bias[h][n(query)][m(key)]
  for (int idx = t; idx < 32768; idx += 256){
    int i  = idx >> 14;
    int hh = (idx >> 12) & 3;
    int n  = (idx >> 6) & 63;
    int m  = idx & 63;
    int tt = (((n>>3)-(m>>3)+7)*15) + ((n&7)-(m&7)+7);
    biasT[idx] = pos3[i][tt][hh];
  }
}

// per-head attention: QK^T -> +bias -> softmax -> P(LDS) -> PV, oo = O^T frags
__device__ __forceinline__ void attn_head(u16* lds, u16* P, const float* bt,
                                          const short8v* qf, const short8v* kf,
                                          const float4v* bv, int hp, int q16, int g,
                                          float4v (&oo)[2][4]){
  const short8v z8 = {0,0,0,0,0,0,0,0};
  // S^T[key][tok] = K Q^T
  float4v s[4][4];
  #pragma unroll
  for (int kt=0;kt<4;++kt)
    #pragma unroll
    for (int mt=0;mt<4;++mt)
      s[kt][mt] = (float4v){0.f,0.f,0.f,0.f};
  __builtin_amdgcn_s_setprio(1);
  #pragma unroll
  for (int kt=0;kt<4;++kt)
    #pragma unroll
    for (int mt=0;mt<4;++mt)
      s[kt][mt] = __builtin_amdgcn_mfma_f32_16x16x32_bf16(kf[kt], qf[mt], s[kt][mt], 0,0,0);
  __builtin_amdgcn_s_setprio(0);
  // scale + bias (prefetched in bv[kt*4+mt])
  #pragma unroll
  for (int kt=0;kt<4;++kt)
    #pragma unroll
    for (int mt=0;mt<4;++mt)
      s[kt][mt] = s[kt][mt]*0.20412414523193154f + bv[kt*4+mt];
  // softmax over key
  #pragma unroll
  for (int mt=0;mt<4;++mt){
    float mx = s[0][mt][0];
    #pragma unroll
    for (int kt=0;kt<4;++kt)
      #pragma unroll
      for (int r=0;r<4;++r) mx = fmaxf(mx, s[kt][mt][r]);
    mx = fmaxf(mx, __shfl_xor(mx, 16));
    mx = fmaxf(mx, __shfl_xor(mx, 32));
    float e[4][4]; float sum = 0.f;
    #pragma unroll
    for (int kt=0;kt<4;++kt)
      #pragma unroll
      for (int r=0;r<4;++r){ float t2 = __expf(s[kt][mt][r]-mx); e[kt][r] = t2; sum += t2; }
    sum += __shfl_xor(sum, 16);
    sum += __shfl_xor(sum, 32);
    const float inv = 1.0f / sum;
    #pragma unroll
    for (int kt=0;kt<4;++kt){
      ushort4v pk = { f2bf(e[kt][0]*inv), f2bf(e[kt][1]*inv), f2bf(e[kt][2]*inv), f2bf(e[kt][3]*inv) };
      *(ushort4v*)&P[(mt*16+q16)*PLD + kt*16 + g*4] = pk;
    }
  }
  // V^T fragments
  short8v vf[2][2];
  #pragma unroll
  for (int dt=0;dt<2;++dt){
    const int d  = dt*16 + q16;
    const int dc = (d < 24) ? d : 0;
    #pragma unroll
    for (int kc=0;kc<2;++kc){
      short8v vv = *(const short8v*)&lds[VS_OFF + (hp*24 + dc)*VSLD + kc*32 + g*8];
      vf[dt][kc] = (d < 24) ? vv : z8;
    }
  }
  // O^T[d][tok] = V^T P^T
  #pragma unroll
  for (int dt=0;dt<2;++dt)
    #pragma unroll
    for (int mt=0;mt<4;++mt) oo[dt][mt] = (float4v){0.f,0.f,0.f,0.f};
  #pragma unroll
  for (int mt=0;mt<4;++mt){
    #pragma unroll
    for (int kc=0;kc<2;++kc){
      short8v pf = *(const short8v*)&P[(mt*16+q16)*PLD + kc*32 + g*8];
      __builtin_amdgcn_s_setprio(1);
      #pragma unroll
      for (int dt=0;dt<2;++dt)
        oo[dt][mt] = __builtin_amdgcn_mfma_f32_16x16x32_bf16(vf[dt][kc], pf, oo[dt][mt], 0,0,0);
      __builtin_amdgcn_s_setprio(0);
    }
  }
}

// ---------------- fused persistent kernel: 4 windows per block, 4 waves ----------------
__global__ __launch_bounds__(256, 2) void awa_main(
    const float* __restrict__ x, const u16* __restrict__ Wq,
    const u16* __restrict__ Wp, const float* __restrict__ proj_b,
    const float* __restrict__ biasT, float* __restrict__ out){
  extern __shared__ u16 lds[];
  const int tid  = threadIdx.x;
  const int wave = tid >> 6;
  const int lane = tid & 63;
  const int g    = lane >> 4;
  const int q16  = lane & 15;
  const short8v z8 = {0,0,0,0,0,0,0,0};

  // float4-index decomposition for x staging (constant per thread per it)
  // fi = tid + it*256, f = fi*4, rr=f/1536, ss=(f%1536)/192, cc=f%192
  float4v xr[12];
  int gw = blockIdx.x*4;
  {
    const int b0 = gw >> 10, win0 = gw & 1023;
    const size_t xb = ((size_t)b0*65536u + (size_t)((win0>>5)*8)*256u + (size_t)((win0&31)*8)) * 192u;
    #pragma unroll
    for (int it=0; it<12; ++it){
      int f = (tid + it*256) << 2;
      int rr = f/1536, rem = f - rr*1536, ss = rem/192, cc = rem - ss*192;
      xr[it] = *(const float4v*)(x + xb + (size_t)((rr*256+ss)*192+cc));
    }
  }

  for (int wloc = 0; wloc < 4; ++wloc){
    const int b   = gw >> 10;
    const int win = gw & 1023;
    const int h1  = win >> 5, w1 = win & 31;

    // ---- Phase 0': write staged x regs -> Xs bf16 ----
    #pragma unroll
    for (int it=0; it<12; ++it){
      int f = (tid + it*256) << 2;
      int rr = f/1536, rem = f - rr*1536, ss = rem/192, cc = rem - ss*192;
      ushort4v pk = { f2bf(xr[it][0]), f2bf(xr[it][1]), f2bf(xr[it][2]), f2bf(xr[it][3]) };
      *(ushort4v*)&lds[(rr*8+ss)*XLD + cc] = pk;
    }
    SOFT_BAR();

    // ---- Phase 1a: X fragments + first W tile prefetch ----
    short8v xf[4][6];
    #pragma unroll
    for (int mt=0; mt<4; ++mt)
      #pragma unroll
      for (int kc=0; kc<6; ++kc)
        xf[mt][kc] = *(const short8v*)&lds[(mt*16+q16)*XLD + kc*32 + g*8];
    short8v wf[2][6];
    {
      const u16* wb = Wq + (size_t)(wave*16 + q16)*192 + g*8;
      #pragma unroll
      for (int kc=0;kc<6;++kc) wf[0][kc] = *(const short8v*)(wb + kc*32);
    }
    SOFT_BAR();   // Xs dead -> C1/VS writes allowed

    // ---- Phase 1b: C1 = X @ Wq^T, 9 tiles/wave, double-buffered W ----
    #pragma unroll
    for (int t=0; t<9; ++t){
      const int nt = wave + t*4;
      if (t < 8){
        const u16* wb = Wq + (size_t)((nt+4)*16 + q16)*192 + g*8;
        #pragma unroll
        for (int kc=0;kc<6;++kc) wf[(t+1)&1][kc] = *(const short8v*)(wb + kc*32);
      }
      float4v acc[4];
      #pragma unroll
      for (int mt=0;mt<4;++mt) acc[mt] = (float4v){0.f,0.f,0.f,0.f};
      if (t < 6){
        #pragma unroll
        for (int kc=0; kc<6; ++kc)
          #pragma unroll
          for (int mt=0; mt<4; ++mt)
            acc[mt] = __builtin_amdgcn_mfma_f32_16x16x32_bf16(wf[t&1][kc], xf[mt][kc], acc[mt], 0,0,0);
        const int cb = nt*16 + g*4;
        #pragma unroll
        for (int mt=0; mt<4; ++mt){
          ushort4v pk = { f2bf(acc[mt][0]), f2bf(acc[mt][1]), f2bf(acc[mt][2]), f2bf(acc[mt][3]) };
          *(ushort4v*)&lds[(mt*16+q16)*C1LD + cb] = pk;
        }
      } else {
        #pragma unroll
        for (int kc=0; kc<6; ++kc)
          #pragma unroll
          for (int mt=0; mt<4; ++mt)
            acc[mt] = __builtin_amdgcn_mfma_f32_16x16x32_bf16(xf[mt][kc], wf[t&1][kc], acc[mt], 0,0,0);
        const int jj  = nt*16 + q16 - 384;
        const int ii2 = (jj >= 96) ? 1 : 0;
        const int c2  = jj - ii2*96;
        const int hh2 = c2 / 24;
        const int d   = c2 - hh2*24;
        const int vb  = VS_OFF + ((ii2*4 + hh2)*24 + d)*VSLD + g*4;
        #pragma unroll
        for (int mt=0; mt<4; ++mt){
          ushort4v pk = { f2bf(acc[mt][0]), f2bf(acc[mt][1]), f2bf(acc[mt][2]), f2bf(acc[mt][3]) };
          *(ushort4v*)&lds[vb + mt*16] = pk;
        }
      }
    }
    SOFT_BAR();

    // ---- Phase 2a: Q,K fragments for both heads + head0 bias prefetch ----
    short8v qf[2][4], kf[2][4];
    #pragma unroll
    for (int h=0; h<2; ++h){
      const int qb = h*96 + wave*24;
      #pragma unroll
      for (int mt=0; mt<4; ++mt){
        short8v a = *(const short8v*)&lds[(mt*16+q16)*C1LD + qb + g*8];
        short8v c = *(const short8v*)&lds[(mt*16+q16)*C1LD + 192 + qb + g*8];
        qf[h][mt] = (g==3) ? z8 : a;
        kf[h][mt] = (g==3) ? z8 : c;
      }
    }
    float4v bv0[16];
    {
      const float* bt = biasT + wave*4096;
      #pragma unroll
      for (int kt=0;kt<4;++kt)
        #pragma unroll
        for (int mt=0;mt<4;++mt)
          bv0[kt*4+mt] = *(const float4v*)&bt[(mt*16+q16)*64 + kt*16 + g*4];
    }
    SOFT_BAR();   // C1 frag reads done -> P arena usable; bv0 stays in flight

    // ---- Phase 2b: attention, head0 then head1 (bias for h1 issued between) ----
    u16* P = &lds[wave*4608];
    float4v oo0[2][4], oo1[2][4];
    attn_head(lds, P, biasT, qf[0], kf[0], bv0, wave, q16, g, oo0);
    float4v bv1[16];
    {
      const float* bt = biasT + (4+wave)*4096;
      #pragma unroll
      for (int kt=0;kt<4;++kt)
        #pragma unroll
        for (int mt=0;mt<4;++mt)
          bv1[kt*4+mt] = *(const float4v*)&bt[(mt*16+q16)*64 + kt*16 + g*4];
    }
    attn_head(lds, P, biasT, qf[1], kf[1], bv1, 4+wave, q16, g, oo1);
    SOFT_BAR();   // P arena dead -> Ostage writes allowed

    // ---- Phase 2c: next-window x prefetch + O -> Ostage + wp prefetch ----
    if (wloc < 3){
      const int gwn = gw + 1;
      const int bn = gwn >> 10, winn = gwn & 1023;
      const size_t xbn = ((size_t)bn*65536u + (size_t)((winn>>5)*8)*256u + (size_t)((winn&31)*8)) * 192u;
      #pragma unroll
      for (int it=0; it<12; ++it){
        int f = (tid + it*256) << 2;
        int rr = f/1536, rem = f - rr*1536, ss = rem/192, cc = rem - ss*192;
        xr[it] = *(const float4v*)(x + xbn + (size_t)((rr*256+ss)*192+cc));
      }
    }
    #pragma unroll
    for (int h=0; h<2; ++h){
      const int cb = h*96 + wave*24;
      float4v (&oo)[2][4] = (h==0) ? oo0 : oo1;
      #pragma unroll
      for (int dt=0; dt<2; ++dt){
        if (dt==0 || g<2){
          #pragma unroll
          for (int mt=0; mt<4; ++mt){
            ushort4v pk = { f2bf(oo[dt][mt][0]), f2bf(oo[dt][mt][1]),
                            f2bf(oo[dt][mt][2]), f2bf(oo[dt][mt][3]) };
            *(ushort4v*)&lds[(mt*16+q16)*XLD + cb + dt*16 + g*4] = pk;
          }
        }
      }
    }
    short8v wp[2][6];
    {
      const u16* wb = Wp + (size_t)(wave*16 + q16)*192 + g*8;
      #pragma unroll
      for (int kc=0;kc<6;++kc) wp[0][kc] = *(const short8v*)(wb + kc*32);
    }
    SOFT_BAR();   // Ostage visible; xr + wp loads stay in flight

    // ---- Phase 3: out = Ostage @ proj_w^T + b ----
    short8v a2[4][6];
    #pragma unroll
    for (int mt=0; mt<4; ++mt)
      #pragma unroll
      for (int kc=0; kc<6; ++kc)
        a2[mt][kc] = *(const short8v*)&lds[(mt*16+q16)*XLD + kc*32 + g*8];
    #pragma unroll
    for (int t=0; t<3; ++t){
      const int nt = wave + t*4;
      if (t < 2){
        const u16* wb = Wp + (size_t)((nt+4)*16 + q16)*192 + g*8;
        #pragma unroll
        for (int kc=0;kc<6;++kc) wp[(t+1)&1][kc] = *(const short8v*)(wb + kc*32);
      }
      float4v acc[4];
      #pragma unroll
      for (int mt=0;mt<4;++mt) acc[mt] = (float4v){0.f,0.f,0.f,0.f};
      __builtin_amdgcn_s_setprio(1);
      #pragma unroll
      for (int kc=0; kc<6; ++kc)
        #pragma unroll
        for (int mt=0; mt<4; ++mt)
          acc[mt] = __builtin_amdgcn_mfma_f32_16x16x32_bf16(wp[t&1][kc], a2[mt][kc], acc[mt], 0,0,0);
      __builtin_amdgcn_s_setprio(0);
      const int j0 = nt*16 + g*4;
      const float4v pb = *(const float4v*)(proj_b + j0);
      #pragma unroll
      for (int mt=0; mt<4; ++mt){
        const int tok = mt*16 + q16;
        const int l = ((h1*8 + (tok>>3)) << 8) + w1*8 + (tok & 7);
        float4v res = acc[mt] + pb;
        *(float4v*)(out + ((size_t)b*65536u + (size_t)l)*192u + j0) = res;
      }
    }
    ++gw;
    if (wloc < 3) SOFT_BAR();   // a2 reads done -> next window may overwrite Xs
  }
}

extern "C" void kernel_launch(void* const* d_in, const int* in_sizes, int n_in,
                              void* d_out, int out_size, void* d_ws, size_t ws_size,
                              hipStream_t stream){
  const float* x      = (const float*)d_in[0];
  const float* qkv_w  = (const float*)d_in[1];
  const float* proj_w = (const float*)d_in[2];
  const float* proj_b = (const float*)d_in[3];
  const float* ppw    = (const float*)d_in[4];
  const float* ppb    = (const float*)d_in[5];
  const float* ln1g   = (const float*)d_in[6];
  const float* ln1b   = (const float*)d_in[7];
  const float* fc1w   = (const float*)d_in[8];
  const float* fc1b   = (const float*)d_in[9];
  const float* ln2g   = (const float*)d_in[10];
  const float* ln2b   = (const float*)d_in[11];
  const float* fc2w   = (const float*)d_in[12];
  const float* fc2b   = (const float*)d_in[13];
  const float* ln3g   = (const float*)d_in[14];
  const float* ln3b   = (const float*)d_in[15];
  const float* fc3w   = (const float*)d_in[16];
  const float* fc3b   = (const float*)d_in[17];

  u16*   Wq    = (u16*)d_ws;                       // 110592 bf16
  u16*   Wp    = Wq + 110592;                      //  36864 bf16
  float* biasT = (float*)((char*)d_ws + 294912);   //  32768 f32

  prep_convert<<<144, 256, 0, stream>>>(qkv_w, proj_w, Wq, Wp);
  prep_bias<<<1, 256, 0, stream>>>(ppw, ppb, ln1g, ln1b, fc1w, fc1b,
                                   ln2g, ln2b, fc2w, fc2b, ln3g, ln3b,
                                   fc3w, fc3b, biasT);
  awa_main<<<512, 256, LDS_BYTES, stream>>>(x, Wq, Wp, proj_b, biasT, (float*)d_out);
}

// Round 9
// 148.940 us; speedup vs baseline: 1.5087x; 1.5087x over previous
//
#include <hip/hip_runtime.h>

typedef unsigned short u16;
typedef unsigned int u32;
typedef short short8v __attribute__((ext_vector_type(8)));
typedef float float4v __attribute__((ext_vector_type(4)));
typedef unsigned short ushort4v __attribute__((ext_vector_type(4)));

// ---------------- LDS layout (u16 element offsets) ----------------
// Region A: C1qk [64 tok][392]  (Q ch 0..191, K ch 192..383, pad)  = 25088 u16
//   overlays: Xs [64][216] (phase 0/1a), P[wave][64][72] (phase 2b, 4*4608),
//             Ostage [64][216] (phase 2c/3)
// Region B: VS [8 hp][24 d][72 m] (V transposed)                   = 13824 u16
#define XLD   216
#define C1LD  392
#define VSLD  72
#define PLD   72
#define VS_OFF (64*C1LD)
#define LDS_U16 (VS_OFF + 8*24*VSLD)   // 38912 u16
#define LDS_BYTES (LDS_U16*2)          // 77824 B -> 2 blocks/CU

// scale * log2(e): softmax computed in base-2 domain (bias table premultiplied)
#define SC2 (0.20412414523193154f * 1.4426950408889634f)

__device__ __forceinline__ u16 f2bf(float f){
  unsigned u = __builtin_bit_cast(unsigned, f);
  return (u16)((u + 0x7FFFu + ((u >> 16) & 1u)) >> 16);
}
// R9 bisect: v_cvt_pk_bf16_f32 inline asm REMOVED (R5-R8 NaN; only opaque
// component of the R5 change-set; guide m240 also flags it as slower than
// scalar casts). Manual RNE pack, the R1-R4-proven path.
__device__ __forceinline__ void st4(u16* p, float4v v){
  ushort4v pk = { f2bf(v[0]), f2bf(v[1]), f2bf(v[2]), f2bf(v[3]) };
  *(ushort4v*)p = pk;
}

// ---------------- prep: convert weights to bf16 ----------------
__global__ void prep_convert(const float* __restrict__ qkv_w, const float* __restrict__ proj_w,
                             u16* __restrict__ Wq, u16* __restrict__ Wp){
  int idx = blockIdx.x*blockDim.x + threadIdx.x;
  const int total = 110592 + 36864;
  for (; idx < total; idx += gridDim.x*blockDim.x){
    if (idx < 110592) Wq[idx] = f2bf(qkv_w[idx]);
    else              Wp[idx-110592] = f2bf(proj_w[idx-110592]);
  }
}

__device__ __forceinline__ void lnrelu6(float* v, const float* g, const float* b){
  float mu = (v[0]+v[1]+v[2]+v[3]+v[4]+v[5]) * (1.0f/6.0f);
  float var = 0.f;
  #pragma unroll
  for (int j=0;j<6;++j){ float d = v[j]-mu; var += d*d; }
  var *= (1.0f/6.0f);
  float inv = rsqrtf(var + 1e-5f);
  #pragma unroll
  for (int j=0;j<6;++j) v[j] = fmaxf((v[j]-mu)*inv*g[j] + b[j], 0.f);
}

// ---------------- prep: rel-pos bias table, biasT[(i*4+h)][n=query][m=key] ----------------
// NOTE: values premultiplied by log2(e) (softmax done in exp2 domain)
__global__ void prep_bias(const float* __restrict__ ppw, const float* __restrict__ ppb,
                          const float* __restrict__ ln1g, const float* __restrict__ ln1b,
                          const float* __restrict__ fc1w, const float* __restrict__ fc1b,
                          const float* __restrict__ ln2g, const float* __restrict__ ln2b,
                          const float* __restrict__ fc2w, const float* __restrict__ fc2b,
                          const float* __restrict__ ln3g, const float* __restrict__ ln3b,
                          const float* __restrict__ fc3w, const float* __restrict__ fc3b,
                          float* __restrict__ biasT){
  __shared__ float pos3[2][225][4];
  const int t = threadIdx.x;
  if (t < 225){
    const float dy = (float)(t/15) - 7.0f;
    const float dx = (float)(t%15) - 7.0f;
    for (int i=0;i<2;++i){
      float v[6], y[6];
      #pragma unroll
      for (int j=0;j<6;++j)
        v[j] = dy*ppw[(i*6+j)*2+0] + dx*ppw[(i*6+j)*2+1] + ppb[i*6+j];
      lnrelu6(v, ln1g+i*6, ln1b+i*6);
      #pragma unroll
      for (int j=0;j<6;++j){
        float a = fc1b[i*6+j];
        #pragma unroll
        for (int k=0;k<6;++k) a += v[k]*fc1w[(i*6+j)*6+k];
        y[j] = a;
      }
      lnrelu6(y, ln2g+i*6, ln2b+i*6);
      #pragma unroll
      for (int j=0;j<6;++j){
        float a = fc2b[i*6+j];
        #pragma unroll
        for (int k=0;k<6;++k) a += y[k]*fc2w[(i*6+j)*6+k];
        v[j] = a;
      }
      lnrelu6(v, ln3g+i*6, ln3b+i*6);
      #pragma unroll
      for (int h=0;h<4;++h){
        float a = fc3b[i*4+h];
        #pragma unroll
        for (int k=0;k<6;++k) a += v[k]*fc3w[(i*4+h)*6+k];
        pos3[i][t][h] = a * 1.4426950408889634f;
      }
    }
  }
  __syncthreads();
  for (int idx = t; idx < 32768; idx += 256){
    int i  = idx >> 14;
    int hh = (idx >> 12) & 3;
    int n  = (idx >> 6) & 63;
    int m  = idx & 63;
    int tt = (((n>>3)-(m>>3)+7)*15) + ((n&7)-(m&7)+7);
    biasT[idx] = pos3[i][tt][hh];
  }
}

// per-head attention: QK^T -> +bias -> softmax(exp2, unnormalized P) -> PV -> scale
__device__ __forceinline__ void attn_head(u16* lds, u16* P,
                                          const short8v* qf, const short8v* kf,
                                          const float4v* bv, int hp, int q16, int g,
                                          float4v (&oo)[2][4]){
  const short8v z8 = {0,0,0,0,0,0,0,0};
  // S^T[key][tok] = K Q^T
  float4v s[4][4];
  #pragma unroll
  for (int kt=0;kt<4;++kt)
    #pragma unroll
    for (int mt=0;mt<4;++mt)
      s[kt][mt] = (float4v){0.f,0.f,0.f,0.f};
  __builtin_amdgcn_s_setprio(1);
  #pragma unroll
  for (int kt=0;kt<4;++kt)
    #pragma unroll
    for (int mt=0;mt<4;++mt)
      s[kt][mt] = __builtin_amdgcn_mfma_f32_16x16x32_bf16(kf[kt], qf[mt], s[kt][mt], 0,0,0);
  __builtin_amdgcn_s_setprio(0);
  // scale(log2 domain) + bias (prefetched in bv[kt*4+mt], already *log2e)
  #pragma unroll
  for (int kt=0;kt<4;++kt)
    #pragma unroll
    for (int mt=0;mt<4;++mt)
      s[kt][mt] = s[kt][mt]*SC2 + bv[kt*4+mt];
  // softmax over key: unnormalized exp2, P stored raw, 1/sum folded into O later
  float inv[4];
  #pragma unroll
  for (int mt=0;mt<4;++mt){
    float mx = s[0][mt][0];
    #pragma unroll
    for (int kt=0;kt<4;++kt)
      #pragma unroll
      for (int r=0;r<4;++r) mx = fmaxf(mx, s[kt][mt][r]);
    mx = fmaxf(mx, __shfl_xor(mx, 16));
    mx = fmaxf(mx, __shfl_xor(mx, 32));
    float sum = 0.f;
    #pragma unroll
    for (int kt=0;kt<4;++kt){
      float4v ev;
      #pragma unroll
      for (int r=0;r<4;++r){ float t2 = exp2f(s[kt][mt][r]-mx); ev[r] = t2; sum += t2; }
      st4(&P[(mt*16+q16)*PLD + kt*16 + g*4], ev);
    }
    sum += __shfl_xor(sum, 16);
    sum += __shfl_xor(sum, 32);
    inv[mt] = 1.0f / sum;
  }
  // Compiler fence: P stores above, P loads below (intra-wave, no barrier).
  asm volatile("" ::: "memory");
  // V^T fragments
  short8v vf[2][2];
  #pragma unroll
  for (int dt=0;dt<2;++dt){
    const int d  = dt*16 + q16;
    const int dc = (d < 24) ? d : 0;
    #pragma unroll
    for (int kc=0;kc<2;++kc){
      short8v vv = *(const short8v*)&lds[VS_OFF + (hp*24 + dc)*VSLD + kc*32 + g*8];
      vf[dt][kc] = (d < 24) ? vv : z8;
    }
  }
  // O^T[d][tok] = V^T P^T
  #pragma unroll
  for (int dt=0;dt<2;++dt)
    #pragma unroll
    for (int mt=0;mt<4;++mt) oo[dt][mt] = (float4v){0.f,0.f,0.f,0.f};
  #pragma unroll
  for (int mt=0;mt<4;++mt){
    #pragma unroll
    for (int kc=0;kc<2;++kc){
      short8v pf = *(const short8v*)&P[(mt*16+q16)*PLD + kc*32 + g*8];
      __builtin_amdgcn_s_setprio(1);
      #pragma unroll
      for (int dt=0;dt<2;++dt)
        oo[dt][mt] = __builtin_amdgcn_mfma_f32_16x16x32_bf16(vf[dt][kc], pf, oo[dt][mt], 0,0,0);
      __builtin_amdgcn_s_setprio(0);
    }
  }
  // fold 1/sum (per query token = per (mt,q16): uniform across this lane's 4 elems)
  #pragma unroll
  for (int dt=0;dt<2;++dt)
    #pragma unroll
    for (int mt=0;mt<4;++mt) oo[dt][mt] *= inv[mt];
}

// ---------------- fused main kernel: one 8x8 window per block, 4 waves ----------------
__global__ __launch_bounds__(256, 2) void awa_main(
    const float* __restrict__ x, const u16* __restrict__ Wq,
    const u16* __restrict__ Wp, const float* __restrict__ proj_b,
    const float* __restrict__ biasT, float* __restrict__ out){
  extern __shared__ u16 lds[];
  const int tid  = threadIdx.x;
  const int wave = tid >> 6;
  const int lane = tid & 63;
  const int g    = lane >> 4;
  const int q16  = lane & 15;
  const int bid  = blockIdx.x;
  const int b    = bid >> 10;
  const int win  = bid & 1023;
  const int h1   = win >> 5, w1 = win & 31;
  const size_t xbase = ((size_t)b*65536u + (size_t)(h1*8)*256u + (size_t)(w1*8)) * 192u;
  const short8v z8 = {0,0,0,0,0,0,0,0};

  // ---- Phase 0: stage x window [64 tok][192 ch] -> bf16 Xs ----
  {
    float4v xr[12];
    #pragma unroll
    for (int it=0; it<12; ++it){
      int f = (tid + it*256) << 2;
      int rr = f/1536, rem = f - rr*1536, ss = rem/192, cc = rem - ss*192;
      xr[it] = *(const float4v*)(x + xbase + (size_t)((rr*256+ss)*192+cc));
    }
    #pragma unroll
    for (int it=0; it<12; ++it){
      int f = (tid + it*256) << 2;
      int rr = f/1536, rem = f - rr*1536, ss = rem/192, cc = rem - ss*192;
      st4(&lds[(rr*8+ss)*XLD + cc], xr[it]);
    }
  }
  __syncthreads();

  // ---- Phase 1a: X fragments + first two W tiles in flight ----
  short8v xf[4][6];
  #pragma unroll
  for (int mt=0; mt<4; ++mt)
    #pragma unroll
    for (int kc=0; kc<6; ++kc)
      xf[mt][kc] = *(const short8v*)&lds[(mt*16+q16)*XLD + kc*32 + g*8];
  short8v wf[3][6];
  #pragma unroll
  for (int pb2=0; pb2<2; ++pb2){
    const u16* wb = Wq + (size_t)((wave + pb2*4)*16 + q16)*192 + g*8;
    #pragma unroll
    for (int kc=0;kc<6;++kc) wf[pb2][kc] = *(const short8v*)(wb + kc*32);
  }
  __syncthreads();   // Xs dead -> C1/VS writes allowed

  // ---- Phase 1b: C1 = X @ Wq^T, 9 tiles/wave, W triple-buffered (depth 2) ----
  #pragma unroll
  for (int t=0; t<9; ++t){
    const int nt = wave + t*4;
    if (t < 7){
      const u16* wb = Wq + (size_t)((nt+8)*16 + q16)*192 + g*8;
      #pragma unroll
      for (int kc=0;kc<6;++kc) wf[(t+2)%3][kc] = *(const short8v*)(wb + kc*32);
    }
    float4v acc[4];
    #pragma unroll
    for (int mt=0;mt<4;++mt) acc[mt] = (float4v){0.f,0.f,0.f,0.f};
    if (t < 6){
      // q/k tiles: transposed orientation -> lane holds 4 consecutive channels
      #pragma unroll
      for (int kc=0; kc<6; ++kc)
        #pragma unroll
        for (int mt=0; mt<4; ++mt)
          acc[mt] = __builtin_amdgcn_mfma_f32_16x16x32_bf16(wf[t%3][kc], xf[mt][kc], acc[mt], 0,0,0);
      const int cb = nt*16 + g*4;
      #pragma unroll
      for (int mt=0; mt<4; ++mt)
        st4(&lds[(mt*16+q16)*C1LD + cb], acc[mt]);
    } else {
      // v tiles: normal orientation -> lane holds 4 consecutive tokens, store V^T
      #pragma unroll
      for (int kc=0; kc<6; ++kc)
        #pragma unroll
        for (int mt=0; mt<4; ++mt)
          acc[mt] = __builtin_amdgcn_mfma_f32_16x16x32_bf16(xf[mt][kc], wf[t%3][kc], acc[mt], 0,0,0);
      const int jj  = nt*16 + q16 - 384;
      const int ii2 = (jj >= 96) ? 1 : 0;
      const int c2  = jj - ii2*96;
      const int hh2 = c2 / 24;
      const int d   = c2 - hh2*24;
      const int vb  = VS_OFF + ((ii2*4 + hh2)*24 + d)*VSLD + g*4;
      #pragma unroll
      for (int mt=0; mt<4; ++mt)
        st4(&lds[vb + mt*16], acc[mt]);
    }
  }
  __syncthreads();

  // ---- Phase 2a: Q,K fragments for both heads + head0 bias prefetch ----
  short8v qf[2][4], kf[2][4];
  #pragma unroll
  for (int h=0; h<2; ++h){
    const int qb = h*96 + wave*24;
    #pragma unroll
    for (int mt=0; mt<4; ++mt){
      short8v a = *(const short8v*)&lds[(mt*16+q16)*C1LD + qb + g*8];
      short8v c = *(const short8v*)&lds[(mt*16+q16)*C1LD + 192 + qb + g*8];
      qf[h][mt] = (g==3) ? z8 : a;
      kf[h][mt] = (g==3) ? z8 : c;
    }
  }
  float4v bv0[16];
  {
    const float* bt = biasT + wave*4096;
    #pragma unroll
    for (int kt=0;kt<4;++kt)
      #pragma unroll
      for (int mt=0;mt<4;++mt)
        bv0[kt*4+mt] = *(const float4v*)&bt[(mt*16+q16)*64 + kt*16 + g*4];
  }
  __syncthreads();   // C1 frag reads done -> P arena usable

  // ---- Phase 2b: attention, head0 then head1 (bias for h1 issued between) ----
  u16* P = &lds[wave*4608];
  float4v oo0[2][4], oo1[2][4];
  attn_head(lds, P, qf[0], kf[0], bv0, wave, q16, g, oo0);
  float4v bv1[16];
  {
    const float* bt = biasT + (4+wave)*4096;
    #pragma unroll
    for (int kt=0;kt<4;++kt)
      #pragma unroll
      for (int mt=0;mt<4;++mt)
        bv1[kt*4+mt] = *(const float4v*)&bt[(mt*16+q16)*64 + kt*16 + g*4];
  }
  attn_head(lds, P, qf[1], kf[1], bv1, 4+wave, q16, g, oo1);
  __syncthreads();   // all waves done reading their P

  // ---- Phase 2c: O -> Ostage + all proj weight tiles issued ----
  #pragma unroll
  for (int h=0; h<2; ++h){
    const int cb = h*96 + wave*24;
    float4v (&oo)[2][4] = (h==0) ? oo0 : oo1;
    #pragma unroll
    for (int dt=0; dt<2; ++dt){
      if (dt==0 || g<2){
        #pragma unroll
        for (int mt=0; mt<4; ++mt)
          st4(&lds[(mt*16+q16)*XLD + cb + dt*16 + g*4], oo[dt][mt]);
      }
    }
  }
  short8v wp[3][6];
  #pragma unroll
  for (int pt=0; pt<3; ++pt){
    const u16* wb = Wp + (size_t)((wave + pt*4)*16 + q16)*192 + g*8;
    #pragma unroll
    for (int kc=0;kc<6;++kc) wp[pt][kc] = *(const short8v*)(wb + kc*32);
  }
  __syncthreads();   // Ostage visible

  // ---- Phase 3: out = Ostage @ proj_w^T + b ----
  short8v a2[4][6];
  #pragma unroll
  for (int mt=0; mt<4; ++mt)
    #pragma unroll
    for (int kc=0; kc<6; ++kc)
      a2[mt][kc] = *(const short8v*)&lds[(mt*16+q16)*XLD + kc*32 + g*8];
  #pragma unroll
  for (int t=0; t<3; ++t){
    const int nt = wave + t*4;
    float4v acc[4];
    #pragma unroll
    for (int mt=0;mt<4;++mt) acc[mt] = (float4v){0.f,0.f,0.f,0.f};
    #pragma unroll
    for (int kc=0; kc<6; ++kc)
      #pragma unroll
      for (int mt=0; mt<4; ++mt)
        acc[mt] = __builtin_amdgcn_mfma_f32_16x16x32_bf16(wp[t][kc], a2[mt][kc], acc[mt], 0,0,0);
    const int j0 = nt*16 + g*4;
    const float4v pb = *(const float4v*)(proj_b + j0);
    #pragma unroll
    for (int mt=0; mt<4; ++mt){
      const int tok = mt*16 + q16;
      const int l = ((h1*8 + (tok>>3)) << 8) + w1*8 + (tok & 7);
      float4v res = acc[mt] + pb;
      *(float4v*)(out + ((size_t)b*65536u + (size_t)l)*192u + j0) = res;
    }
  }
}

extern "C" void kernel_launch(void* const* d_in, const int* in_sizes, int n_in,
                              void* d_out, int out_size, void* d_ws, size_t ws_size,
                              hipStream_t stream){
  const float* x      = (const float*)d_in[0];
  const float* qkv_w  = (const float*)d_in[1];
  const float* proj_w = (const float*)d_in[2];
  const float* proj_b = (const float*)d_in[3];
  const float* ppw    = (const float*)d_in[4];
  const float* ppb    = (const float*)d_in[5];
  const float* ln1g   = (const float*)d_in[6];
  const float* ln1b   = (const float*)d_in[7];
  const float* fc1w   = (const float*)d_in[8];
  const float* fc1b   = (const float*)d_in[9];
  const float* ln2g   = (const float*)d_in[10];
  const float* ln2b   = (const float*)d_in[11];
  const float* fc2w   = (const float*)d_in[12];
  const float* fc2b   = (const float*)d_in[13];
  const float* ln3g   = (const float*)d_in[14];
  const float* ln3b   = (const float*)d_in[15];
  const float* fc3w   = (const float*)d_in[16];
  const float* fc3b   = (const float*)d_in[17];

  u16*   Wq    = (u16*)d_ws;                       // 110592 bf16
  u16*   Wp    = Wq + 110592;                      //  36864 bf16
  float* biasT = (float*)((char*)d_ws + 294912);   //  32768 f32

  prep_convert<<<144, 256, 0, stream>>>(qkv_w, proj_w, Wq, Wp);
  prep_bias<<<1, 256, 0, stream>>>(ppw, ppb, ln1g, ln1b, fc1w, fc1b,
                                   ln2g, ln2b, fc2w, fc2b, ln3g, ln3b,
                                   fc3w, fc3b, biasT);
  awa_main<<<2048, 256, LDS_BYTES, stream>>>(x, Wq, Wp, proj_b, biasT, (float*)d_out);
}